// Round 1
// baseline (426.826 us; speedup 1.0000x reference)
//
#include <hip/hip_runtime.h>
#include <math.h>

// B=2, L=2048, H=8, E=64. Outputs: V [B,L,H,E] then SA [B,H,L,S], fp32.
#define L_DIM 2048
#define H_DIM 8
#define ROWSTRIDE 512                 // H*E floats between consecutive l
#define NT 512
// 0.125 * log2(e): scores computed in log2 domain -> raw v_exp_f32 for softmax
#define QSCALE 0.18033688011112042f

typedef __attribute__((ext_vector_type(8))) short short8;
typedef __attribute__((ext_vector_type(4))) float floatx4;

__device__ __forceinline__ unsigned short f2bf(float f) {
    // round-half-up (2 VALU ops); identical numerics to previous kernel
    unsigned int u = __builtin_bit_cast(unsigned int, f);
    return (unsigned short)((u + 0x8000u) >> 16);
}

__device__ __forceinline__ float fexp2(float x) {
#if __has_builtin(__builtin_amdgcn_exp2f)
    return __builtin_amdgcn_exp2f(x);   // raw v_exp_f32
#else
    return exp2f(x);
#endif
}

__device__ __forceinline__ short8 pack8(float4 a, float4 b) {
    union { unsigned short us[8]; short8 v; } pk;
    pk.us[0]=f2bf(a.x); pk.us[1]=f2bf(a.y); pk.us[2]=f2bf(a.z); pk.us[3]=f2bf(a.w);
    pk.us[4]=f2bf(b.x); pk.us[5]=f2bf(b.y); pk.us[6]=f2bf(b.z); pk.us[7]=f2bf(b.w);
    return pk.v;
}

__device__ __forceinline__ short8 pack8q(float4 a, float4 b) {
    union { unsigned short us[8]; short8 v; } pk;
    pk.us[0]=f2bf(a.x*QSCALE); pk.us[1]=f2bf(a.y*QSCALE);
    pk.us[2]=f2bf(a.z*QSCALE); pk.us[3]=f2bf(a.w*QSCALE);
    pk.us[4]=f2bf(b.x*QSCALE); pk.us[5]=f2bf(b.y*QSCALE);
    pk.us[6]=f2bf(b.z*QSCALE); pk.us[7]=f2bf(b.w*QSCALE);
    return pk.v;
}

// 256 blocks = 16 bh x 16 p. Each block sequentially owns q-tiles {31-p, p}
// of one (b,h): exactly 33 s-tiles/pass per block -> every CU does identical
// work (dispatch-independent balance; the old 512-block pair-swizzle collided
// mod 256 and co-scheduled same-qt blocks).
// bh = bid&15 so all blocks of a head land on one XCD (K+V of 2 heads = 2 MB
// in the 4 MB XCD L2).
// Pass 1 (m/l): K fragments loaded straight from global (L2-hit) into
// registers -> NO LDS, NO barriers; the two 4-wave s-groups run decoupled.
// Pass 2: K again from registers; V transpose-staged to LDS, double-buffered
// (1 barrier/iter), V loads issued at iter top so latency hides under
// QK+softmax+PV. Vt writes column-XOR-swizzled: 8-way -> 4-way bank conflict.
__global__ __launch_bounds__(NT, 2)
void attn_mfma3(const float* __restrict__ Q, const float* __restrict__ K,
                const float* __restrict__ Vv, float* __restrict__ outV,
                float* __restrict__ outSA)
{
    __shared__ __align__(16) unsigned char smem[56320];
    unsigned short* Vt = (unsigned short*)(smem);            // [2 grp][2 buf][64][72]
    unsigned short* Ps = (unsigned short*)(smem + 36864);    // [2 grp][64][72]
    float* Ml = (float*)(smem + 55296);                      // [2][64]
    float* Ll = (float*)(smem + 55808);                      // [2][64]
    float* Ob = (float*)(smem);                              // [64][65] fp32, overlaps Vt

    const int t   = threadIdx.x;
    const int g   = t >> 8;            // s-group
    const int u   = t & 255;           // index within group
    const int bid = blockIdx.x;
    const int bh  = bid & 15;          // same-head blocks share an XCD L2
    const int pp  = bid >> 4;          // q-tile pair selector 0..15
    const int h   = bh & 7;
    const int b   = bh >> 3;

    const int lane = t & 63;
    const int wg   = (t >> 6) & 3;     // wave within group: rows 16wg..16wg+15
    const int l15  = lane & 15;
    const int quad = lane >> 4;

    const int ksr = u >> 2, kse = (u & 3) * 16;   // V staging: 4 threads/row
    const int vswz = ksr ^ (kse >> 1);            // col-swizzle: spreads banks 8->16

    const float* Qb = Q  + (size_t)b * L_DIM * ROWSTRIDE + h * 64;
    const float* Kb = K  + (size_t)b * L_DIM * ROWSTRIDE + h * 64;
    const float* Vb = Vv + (size_t)b * L_DIM * ROWSTRIDE + h * 64;
    float* saBase = outSA + (size_t)(b * H_DIM + h) * L_DIM * L_DIM;

    unsigned short* myVt = Vt + g * 9216;   // shorts: 2 bufs x 4608
    unsigned short* myPs = Ps + g * 4608;

    for (int qsel = 0; qsel < 2; ++qsel) {
        const int qt = qsel ? pp : (31 - pp);   // heavy tile first
        const int q0 = qt << 6;
        const int ntiles = qt + 1;
        const int niter  = (ntiles + 1) >> 1;

        // ---- Q fragments straight from global (scale folded) ----
        short8 aQ0, aQ1;
        {
            const float* qsrc = Qb + (size_t)(q0 + 16 * wg + l15) * ROWSTRIDE + quad * 8;
            aQ0 = pack8q(*(const float4*)(qsrc),      *(const float4*)(qsrc + 4));
            aQ1 = pack8q(*(const float4*)(qsrc + 32), *(const float4*)(qsrc + 36));
        }

        // =================== PASS 1: row max & denom (barrier-free) ===================
        float m_r[4], l_r[4];
#pragma unroll
        for (int r = 0; r < 4; ++r) { m_r[r] = -INFINITY; l_r[r] = 0.f; }

        for (int st = g; st < ntiles; st += 2) {
            const int s0 = st << 6;
            const float* kbase = Kb + (size_t)(s0 + l15) * ROWSTRIDE + quad * 8;
            float4 kr[16];
#pragma unroll
            for (int j = 0; j < 4; ++j) {
                const float* kj = kbase + (size_t)(16 * j) * ROWSTRIDE;
                kr[4*j+0] = *(const float4*)(kj);
                kr[4*j+1] = *(const float4*)(kj + 4);
                kr[4*j+2] = *(const float4*)(kj + 32);
                kr[4*j+3] = *(const float4*)(kj + 36);
            }
            floatx4 d[4];
#pragma unroll
            for (int j = 0; j < 4; ++j) {
                short8 b0 = pack8(kr[4*j+0], kr[4*j+1]);
                short8 b1 = pack8(kr[4*j+2], kr[4*j+3]);
                floatx4 acc = {0.f, 0.f, 0.f, 0.f};
                acc = __builtin_amdgcn_mfma_f32_16x16x32_bf16(aQ0, b0, acc, 0, 0, 0);
                acc = __builtin_amdgcn_mfma_f32_16x16x32_bf16(aQ1, b1, acc, 0, 0, 0);
                d[j] = acc;
            }
            const bool diag = (st == qt);
#pragma unroll
            for (int r = 0; r < 4; ++r) {
                const int lrow = q0 + 16 * wg + quad * 4 + r;
                float v0 = d[0][r], v1 = d[1][r], v2 = d[2][r], v3 = d[3][r];
                if (diag) {
                    v0 = (s0 +  0 + l15 <= lrow) ? v0 : -INFINITY;
                    v1 = (s0 + 16 + l15 <= lrow) ? v1 : -INFINITY;
                    v2 = (s0 + 32 + l15 <= lrow) ? v2 : -INFINITY;
                    v3 = (s0 + 48 + l15 <= lrow) ? v3 : -INFINITY;
                }
                float vm = fmaxf(fmaxf(v0, v1), fmaxf(v2, v3));
#pragma unroll
                for (int mk = 1; mk < 16; mk <<= 1) vm = fmaxf(vm, __shfl_xor(vm, mk));
                const float mnew = fmaxf(m_r[r], vm);
                float es = fexp2(v0 - mnew) + fexp2(v1 - mnew) +
                           fexp2(v2 - mnew) + fexp2(v3 - mnew);
#pragma unroll
                for (int mk = 1; mk < 16; mk <<= 1) es += __shfl_xor(es, mk);
                l_r[r] = l_r[r] * fexp2(m_r[r] - mnew) + es;
                m_r[r] = mnew;
            }
        }

        // ---- combine m/l across the two s-groups ----
        __syncthreads();                                   // A
        if (l15 == 0) {
#pragma unroll
            for (int r = 0; r < 4; ++r) {
                const int row = 16 * wg + quad * 4 + r;
                Ml[g * 64 + row] = m_r[r];
                Ll[g * 64 + row] = l_r[r];
            }
        }
        __syncthreads();                                   // B
        float mfin[4], invl[4];
#pragma unroll
        for (int r = 0; r < 4; ++r) {
            const int row = 16 * wg + quad * 4 + r;
            float m0 = Ml[row], m1 = Ml[64 + row];
            float l0 = Ll[row], l1 = Ll[64 + row];
            float mf = fmaxf(m0, m1);              // finite: group 0 always has >=1 tile
            float lf = l0 * fexp2(m0 - mf) + l1 * fexp2(m1 - mf);  // 0*0=0 for idle group
            mfin[r] = mf;
            invl[r] = 1.0f / lf;
        }

        // =================== PASS 2: SA write + PV ===================
        floatx4 oacc[4];
#pragma unroll
        for (int j = 0; j < 4; ++j) oacc[j] = (floatx4){0.f, 0.f, 0.f, 0.f};

        // prologue: stage V tile st=g into buf0
        if (g < ntiles) {
            const float* src = Vb + (size_t)((g << 6) + ksr) * ROWSTRIDE + kse;
            float4 f0 = *(const float4*)(src);
            float4 f1 = *(const float4*)(src + 4);
            float4 f2 = *(const float4*)(src + 8);
            float4 f3 = *(const float4*)(src + 12);
            unsigned short* vtw = myVt + vswz;
            vtw[(kse+ 0)*72] = f2bf(f0.x); vtw[(kse+ 1)*72] = f2bf(f0.y);
            vtw[(kse+ 2)*72] = f2bf(f0.z); vtw[(kse+ 3)*72] = f2bf(f0.w);
            vtw[(kse+ 4)*72] = f2bf(f1.x); vtw[(kse+ 5)*72] = f2bf(f1.y);
            vtw[(kse+ 6)*72] = f2bf(f1.z); vtw[(kse+ 7)*72] = f2bf(f1.w);
            vtw[(kse+ 8)*72] = f2bf(f2.x); vtw[(kse+ 9)*72] = f2bf(f2.y);
            vtw[(kse+10)*72] = f2bf(f2.z); vtw[(kse+11)*72] = f2bf(f2.w);
            vtw[(kse+12)*72] = f2bf(f3.x); vtw[(kse+13)*72] = f2bf(f3.y);
            vtw[(kse+14)*72] = f2bf(f3.z); vtw[(kse+15)*72] = f2bf(f3.w);
        }
        __syncthreads();                                   // C

        for (int it = 0; it < niter; ++it) {
            const int st = 2 * it + g;
            const bool active = (st < ntiles);
            const int stn = st + 2;
            const bool nact = (stn < ntiles);
            // issue next-tile V loads unconditionally (clamped addr) so they sit
            // in flight under the whole compute phase (T14 async-split)
            const int stc = nact ? stn : (ntiles - 1);
            const float* vsrc = Vb + (size_t)((stc << 6) + ksr) * ROWSTRIDE + kse;
            float4 f0 = *(const float4*)(vsrc);
            float4 f1 = *(const float4*)(vsrc + 4);
            float4 f2 = *(const float4*)(vsrc + 8);
            float4 f3 = *(const float4*)(vsrc + 12);

            if (active) {
                const int s0 = st << 6;
                const float* kbase = Kb + (size_t)(s0 + l15) * ROWSTRIDE + quad * 8;
                float4 kr[16];
#pragma unroll
                for (int j = 0; j < 4; ++j) {
                    const float* kj = kbase + (size_t)(16 * j) * ROWSTRIDE;
                    kr[4*j+0] = *(const float4*)(kj);
                    kr[4*j+1] = *(const float4*)(kj + 4);
                    kr[4*j+2] = *(const float4*)(kj + 32);
                    kr[4*j+3] = *(const float4*)(kj + 36);
                }
                floatx4 d[4];
#pragma unroll
                for (int j = 0; j < 4; ++j) {
                    short8 b0 = pack8(kr[4*j+0], kr[4*j+1]);
                    short8 b1 = pack8(kr[4*j+2], kr[4*j+3]);
                    floatx4 acc = {0.f, 0.f, 0.f, 0.f};
                    acc = __builtin_amdgcn_mfma_f32_16x16x32_bf16(aQ0, b0, acc, 0, 0, 0);
                    acc = __builtin_amdgcn_mfma_f32_16x16x32_bf16(aQ1, b1, acc, 0, 0, 0);
                    d[j] = acc;
                }
                const bool diag = (st == qt);
#pragma unroll
                for (int r = 0; r < 4; ++r) {
                    const int lrow = q0 + 16 * wg + quad * 4 + r;
                    float* sap = saBase + (size_t)lrow * L_DIM + s0 + l15;
                    const float mr = mfin[r], il = invl[r];
#pragma unroll
                    for (int j = 0; j < 4; ++j) {
                        float v = d[j][r];
                        bool ok = !diag || (s0 + 16 * j + l15 <= lrow);
                        float p = ok ? fexp2(v - mr) * il : 0.0f;
                        sap[16 * j] = p;
                        myPs[(16 * wg + quad * 4 + r) * 72 + 16 * j + l15] = f2bf(p);
                    }
                }
                // PV: rows of myPs are wave-private; compiler's lgkmcnt covers the RAW
                short8 aP0 = *(const short8*)&myPs[(16 * wg + l15) * 72 + quad * 8];
                short8 aP1 = *(const short8*)&myPs[(16 * wg + l15) * 72 + 32 + quad * 8];
                const unsigned short* vtr = myVt + (it & 1) * 4608;
#pragma unroll
                for (int j = 0; j < 4; ++j) {
                    const unsigned short* vb = vtr + (16 * j + l15) * 72;
                    short8 bv0 = *(const short8*)&vb[(quad ^ j) * 8];
                    short8 bv1 = *(const short8*)&vb[32 + (quad ^ j) * 8];
                    oacc[j] = __builtin_amdgcn_mfma_f32_16x16x32_bf16(aP0, bv0, oacc[j], 0, 0, 0);
                    oacc[j] = __builtin_amdgcn_mfma_f32_16x16x32_bf16(aP1, bv1, oacc[j], 0, 0, 0);
                }
            }

            if (nact) {   // write prefetched V to the other buffer
                unsigned short* vtw = myVt + ((it + 1) & 1) * 4608 + vswz;
                vtw[(kse+ 0)*72] = f2bf(f0.x); vtw[(kse+ 1)*72] = f2bf(f0.y);
                vtw[(kse+ 2)*72] = f2bf(f0.z); vtw[(kse+ 3)*72] = f2bf(f0.w);
                vtw[(kse+ 4)*72] = f2bf(f1.x); vtw[(kse+ 5)*72] = f2bf(f1.y);
                vtw[(kse+ 6)*72] = f2bf(f1.z); vtw[(kse+ 7)*72] = f2bf(f1.w);
                vtw[(kse+ 8)*72] = f2bf(f2.x); vtw[(kse+ 9)*72] = f2bf(f2.y);
                vtw[(kse+10)*72] = f2bf(f2.z); vtw[(kse+11)*72] = f2bf(f2.w);
                vtw[(kse+12)*72] = f2bf(f3.x); vtw[(kse+13)*72] = f2bf(f3.y);
                vtw[(kse+14)*72] = f2bf(f3.z); vtw[(kse+15)*72] = f2bf(f3.w);
            }
            __syncthreads();                               // one barrier per iter
        }

        // ---- combine partial O across groups (Ob overlaps Vt; safe after barrier) ----
        if (g == 1) {
#pragma unroll
            for (int r = 0; r < 4; ++r) {
                const int row = 16 * wg + quad * 4 + r;
#pragma unroll
                for (int j = 0; j < 4; ++j)
                    Ob[row * 65 + 16 * j + l15] = oacc[j][r];
            }
        }
        __syncthreads();                                   // E
        if (g == 0) {
#pragma unroll
            for (int r = 0; r < 4; ++r) {
                const int row = 16 * wg + quad * 4 + r;
                float* op = outV + ((size_t)b * L_DIM + q0 + row) * ROWSTRIDE + h * 64 + l15;
#pragma unroll
                for (int j = 0; j < 4; ++j)
                    op[16 * j] = oacc[j][r] + Ob[row * 65 + 16 * j + l15];
            }
        }

        // ---- zero-fill SA above the diagonal tile (d_out is poisoned) ----
        {
            const int z0 = ntiles << 6;
            const int zr = t >> 3;               // 64 rows, 8 threads/row
            float* rowp = saBase + (size_t)(q0 + zr) * L_DIM;
            const float4 zf = {0.f, 0.f, 0.f, 0.f};
            for (int s = z0 + (t & 7) * 4; s < L_DIM; s += 32)
                *(float4*)(rowp + s) = zf;
        }
        // next qsel's first LDS writes (Ml/Ll after barrier A, Vt after B) are
        // barrier-ordered after this qsel's Ob reads -> no extra barrier needed
    }
}

extern "C" void kernel_launch(void* const* d_in, const int* in_sizes, int n_in,
                              void* d_out, int out_size, void* d_ws, size_t ws_size,
                              hipStream_t stream) {
    const float* Q  = (const float*)d_in[0];
    const float* K  = (const float*)d_in[1];
    const float* Vv = (const float*)d_in[2];
    float* out   = (float*)d_out;
    float* outV  = out;                                       // [B,L,H,E]
    float* outSA = out + (size_t)2 * L_DIM * H_DIM * 64;      // [B,H,L,S]

    dim3 grid(256);              // 16 (b,h) x 16 complementary q-tile pairs
    dim3 block(NT);
    attn_mfma3<<<grid, block, 0, stream>>>(Q, K, Vv, outV, outSA);
}

// Round 2
// 348.581 us; speedup vs baseline: 1.2245x; 1.2245x over previous
//
#include <hip/hip_runtime.h>
#include <math.h>

// B=2, L=2048, H=8, E=64. Outputs: V [B,L,H,E] then SA [B,H,L,S], fp32.
#define L_DIM 2048
#define H_DIM 8
#define ROWSTRIDE 512                 // H*E floats between consecutive l
#define NT 512
// 0.125 * log2(e): scores computed in log2 domain -> raw v_exp_f32 for softmax
#define QSCALE 0.18033688011112042f

typedef __attribute__((ext_vector_type(8))) short short8;
typedef __attribute__((ext_vector_type(4))) float floatx4;

__device__ __forceinline__ unsigned short f2bf(float f) {
    // round-half-up (2 VALU ops); identical numerics to previous kernels
    unsigned int u = __builtin_bit_cast(unsigned int, f);
    return (unsigned short)((u + 0x8000u) >> 16);
}

__device__ __forceinline__ float fexp2(float x) {
#if __has_builtin(__builtin_amdgcn_exp2f)
    return __builtin_amdgcn_exp2f(x);   // raw v_exp_f32
#else
    return exp2f(x);
#endif
}

__device__ __forceinline__ short8 pack8(float4 a, float4 b) {
    union { unsigned short us[8]; short8 v; } pk;
    pk.us[0]=f2bf(a.x); pk.us[1]=f2bf(a.y); pk.us[2]=f2bf(a.z); pk.us[3]=f2bf(a.w);
    pk.us[4]=f2bf(b.x); pk.us[5]=f2bf(b.y); pk.us[6]=f2bf(b.z); pk.us[7]=f2bf(b.w);
    return pk.v;
}

__device__ __forceinline__ short8 pack8q(float4 a, float4 b) {
    union { unsigned short us[8]; short8 v; } pk;
    pk.us[0]=f2bf(a.x*QSCALE); pk.us[1]=f2bf(a.y*QSCALE);
    pk.us[2]=f2bf(a.z*QSCALE); pk.us[3]=f2bf(a.w*QSCALE);
    pk.us[4]=f2bf(b.x*QSCALE); pk.us[5]=f2bf(b.y*QSCALE);
    pk.us[6]=f2bf(b.z*QSCALE); pk.us[7]=f2bf(b.w*QSCALE);
    return pk.v;
}

// Swizzled short-index within a [64][64] bf16 tile. Rows are 128B = 8 x 16B
// blocks; phys block = logical block ^ (row&7). All ds_read_b128 fragment
// reads (rows vary with l15, col-block fixed per quad) then hit the
// 8-access/bank floor instead of a 16-way conflict. Bijective per row.
__device__ __forceinline__ int swz(int row, int col) {
    return (row << 6) + ((((col >> 3) ^ (row & 7)) << 3) | (col & 7));
}

// 512 blocks x 512 threads (8 waves). Mapping: c=bid&255, hf=bid>>8,
// bh=c&15 (head pinned to XCD bh&7 -> K+V fp32 of 2 (b,h) pairs = 2MB
// L2-resident), p=c>>4, qt = hf ? p : 31-p. Under the natural (c, c+256)
// 2-blocks/CU co-residency this pairs complementary q-tiles: per-CU work is
// a uniform 33 tiles/pass (round-0's mapping co-scheduled same-qt pairs:
// 64 tiles worst-CU).
// All 8 waves share ONE staged 64x64 K (and V^T) tile per iteration; the two
// 4-wave s-groups split its s-COLUMNS 32/32 (group-partial m/l and O,
// combined via LDS as before). Single barrier per iteration: next tile's
// global loads are issued at iter top into registers, LDS-written after
// compute (T14 async-split), so L2 latency hides under QK+softmax+PV.
__global__ __launch_bounds__(NT, 4)
void attn_mfma4(const float* __restrict__ Q, const float* __restrict__ K,
                const float* __restrict__ Vv, float* __restrict__ outV,
                float* __restrict__ outSA)
{
    __shared__ __align__(16) unsigned char smem[41984];
    unsigned short* Ks = (unsigned short*)(smem);           // [2 buf][64][64] swz, row=s col=e
    unsigned short* Vt = (unsigned short*)(smem + 16384);   // [2 buf][64][64] swz, row=e col=s
    unsigned short* Ps = (unsigned short*)(smem + 32768);   // [64][64] swz (wave/group-private slices)
    float* Ml = (float*)(smem + 40960);                     // [2][64]
    float* Ll = (float*)(smem + 41472);                     // [2][64]
    float* Ob = (float*)(smem);                             // [64][65] fp32, overlays Ks/Vt head

    const int t    = threadIdx.x;
    const int lane = t & 63;
    const int w    = t >> 6;           // wave 0..7
    const int g    = w >> 2;           // s-column group: cols [32g, 32g+32)
    const int wg   = w & 3;            // wave-in-group: rows 16wg..16wg+15
    const int l15  = lane & 15;
    const int quad = lane >> 4;
    const int gc   = g << 5;           // group column base within tile

    const int bid = blockIdx.x;
    const int c   = bid & 255;
    const int hf  = bid >> 8;
    const int bh  = c & 15;
    const int p   = c >> 4;
    const int qt  = hf ? p : (31 - p);
    const int h   = bh & 7;
    const int b   = bh >> 3;
    const int q0  = qt << 6;
    const int ntiles = qt + 1;

    const float* Qb = Q  + (size_t)b * L_DIM * ROWSTRIDE + h * 64;
    const float* Kb = K  + (size_t)b * L_DIM * ROWSTRIDE + h * 64;
    const float* Vb = Vv + (size_t)b * L_DIM * ROWSTRIDE + h * 64;
    float* saBase = outSA + (size_t)(b * H_DIM + h) * L_DIM * L_DIM;

    // staging mapping: thread t handles tile row sr, 8 elems at col sc
    const int sr = t >> 3, sc = (t & 7) << 3;
    const int kswz = swz(sr, sc);      // 16B-aligned short8 dest for K staging

    // ---- Q fragments straight from global (scale folded), once per block ----
    short8 aQ0, aQ1;
    {
        const float* qsrc = Qb + (size_t)(q0 + 16 * wg + l15) * ROWSTRIDE + quad * 8;
        aQ0 = pack8q(*(const float4*)(qsrc),      *(const float4*)(qsrc + 4));
        aQ1 = pack8q(*(const float4*)(qsrc + 32), *(const float4*)(qsrc + 36));
    }

    // =================== PASS 1: row max & denom ===================
    float m_r[4], l_r[4];
#pragma unroll
    for (int r = 0; r < 4; ++r) { m_r[r] = -INFINITY; l_r[r] = 0.f; }

    {   // prologue: stage K tile 0 into buf 0
        const float* src = Kb + (size_t)sr * ROWSTRIDE + sc;
        *(short8*)&Ks[kswz] = pack8(*(const float4*)src, *(const float4*)(src + 4));
    }
    __syncthreads();

    for (int st = 0; st < ntiles; ++st) {
        const int cur = st & 1;
        // prefetch next K tile into regs (clamped addr on last iter)
        const int stp = (st + 1 < ntiles) ? (st + 1) : st;
        const float* ksrc = Kb + (size_t)((stp << 6) + sr) * ROWSTRIDE + sc;
        float4 kf0 = *(const float4*)(ksrc);
        float4 kf1 = *(const float4*)(ksrc + 4);

        const unsigned short* Kc = Ks + (cur << 12);
        floatx4 d[2];
#pragma unroll
        for (int jj = 0; jj < 2; ++jj) {
            const int sb = gc + (jj << 4) + l15;
            short8 b0 = *(const short8*)&Kc[swz(sb, quad * 8)];
            short8 b1 = *(const short8*)&Kc[swz(sb, 32 + quad * 8)];
            floatx4 acc = {0.f, 0.f, 0.f, 0.f};
            acc = __builtin_amdgcn_mfma_f32_16x16x32_bf16(aQ0, b0, acc, 0, 0, 0);
            acc = __builtin_amdgcn_mfma_f32_16x16x32_bf16(aQ1, b1, acc, 0, 0, 0);
            d[jj] = acc;
        }
        const int s0 = st << 6;
        const bool diag = (st == qt);
#pragma unroll
        for (int r = 0; r < 4; ++r) {
            const int lrow = q0 + 16 * wg + quad * 4 + r;
            float v0 = d[0][r], v1 = d[1][r];
            if (diag) {
                v0 = (s0 + gc +  0 + l15 <= lrow) ? v0 : -INFINITY;
                v1 = (s0 + gc + 16 + l15 <= lrow) ? v1 : -INFINITY;
            }
            float vm = fmaxf(v0, v1);
#pragma unroll
            for (int mk = 1; mk < 16; mk <<= 1) vm = fmaxf(vm, __shfl_xor(vm, mk));
            const float mnew = fmaxf(m_r[r], vm);
            // group-1 rows <32 of a diagonal tile are FULLY masked -> mnew=-inf;
            // msafe avoids (-inf)-(-inf)=NaN while leaving l=0, m=-inf intact.
            const float msafe = (mnew == -INFINITY) ? 0.0f : mnew;
            float es = fexp2(v0 - msafe) + fexp2(v1 - msafe);
#pragma unroll
            for (int mk = 1; mk < 16; mk <<= 1) es += __shfl_xor(es, mk);
            l_r[r] = l_r[r] * fexp2(m_r[r] - msafe) + es;
            m_r[r] = mnew;
        }
        if (st + 1 < ntiles)
            *(short8*)&Ks[((cur ^ 1) << 12) + kswz] = pack8(kf0, kf1);
        __syncthreads();
    }

    // ---- combine m/l across the two s-column groups ----
    if (l15 == 0) {
#pragma unroll
        for (int r = 0; r < 4; ++r) {
            const int row = 16 * wg + quad * 4 + r;
            Ml[g * 64 + row] = m_r[r];
            Ll[g * 64 + row] = l_r[r];
        }
    }
    {   // pass-2 prologue: stage K and V^T tile 0 into buf 0 (overlaps combine)
        const float* src = Kb + (size_t)sr * ROWSTRIDE + sc;
        *(short8*)&Ks[kswz] = pack8(*(const float4*)src, *(const float4*)(src + 4));
        const float* vsrc = Vb + (size_t)sr * ROWSTRIDE + sc;
        float4 f0 = *(const float4*)(vsrc);
        float4 f1 = *(const float4*)(vsrc + 4);
        Vt[swz(sc + 0, sr)] = f2bf(f0.x); Vt[swz(sc + 1, sr)] = f2bf(f0.y);
        Vt[swz(sc + 2, sr)] = f2bf(f0.z); Vt[swz(sc + 3, sr)] = f2bf(f0.w);
        Vt[swz(sc + 4, sr)] = f2bf(f1.x); Vt[swz(sc + 5, sr)] = f2bf(f1.y);
        Vt[swz(sc + 6, sr)] = f2bf(f1.z); Vt[swz(sc + 7, sr)] = f2bf(f1.w);
    }
    __syncthreads();

    float mfin[4], invl[4];
#pragma unroll
    for (int r = 0; r < 4; ++r) {
        const int row = 16 * wg + quad * 4 + r;
        float m0 = Ml[row], m1 = Ml[64 + row];
        float l0 = Ll[row], l1 = Ll[64 + row];
        float mf = fmaxf(m0, m1);              // finite: group 0 col 0 never masked
        float lf = l0 * fexp2(m0 - mf) + l1 * fexp2(m1 - mf);  // 0*0=0 for all-masked group
        mfin[r] = mf;
        invl[r] = 1.0f / lf;
    }

    // =================== PASS 2: SA write + PV ===================
    floatx4 oacc[4];
#pragma unroll
    for (int j = 0; j < 4; ++j) oacc[j] = (floatx4){0.f, 0.f, 0.f, 0.f};

    for (int st = 0; st < ntiles; ++st) {
        const int cur = st & 1;
        const int stp = (st + 1 < ntiles) ? (st + 1) : st;
        const float* ksrc = Kb + (size_t)((stp << 6) + sr) * ROWSTRIDE + sc;
        const float* vsrc = Vb + (size_t)((stp << 6) + sr) * ROWSTRIDE + sc;
        float4 kf0 = *(const float4*)(ksrc);
        float4 kf1 = *(const float4*)(ksrc + 4);
        float4 vf0 = *(const float4*)(vsrc);
        float4 vf1 = *(const float4*)(vsrc + 4);

        const unsigned short* Kc = Ks + (cur << 12);
        floatx4 d[2];
#pragma unroll
        for (int jj = 0; jj < 2; ++jj) {
            const int sb = gc + (jj << 4) + l15;
            short8 b0 = *(const short8*)&Kc[swz(sb, quad * 8)];
            short8 b1 = *(const short8*)&Kc[swz(sb, 32 + quad * 8)];
            floatx4 acc = {0.f, 0.f, 0.f, 0.f};
            acc = __builtin_amdgcn_mfma_f32_16x16x32_bf16(aQ0, b0, acc, 0, 0, 0);
            acc = __builtin_amdgcn_mfma_f32_16x16x32_bf16(aQ1, b1, acc, 0, 0, 0);
            d[jj] = acc;
        }
        const int s0 = st << 6;
        const bool diag = (st == qt);
#pragma unroll
        for (int r = 0; r < 4; ++r) {
            const int lrow = q0 + 16 * wg + quad * 4 + r;
            float* sap = saBase + (size_t)lrow * L_DIM + s0 + gc + l15;
            const float mr = mfin[r], il = invl[r];
#pragma unroll
            for (int jj = 0; jj < 2; ++jj) {
                float v = d[jj][r];
                bool ok = !diag || (s0 + gc + 16 * jj + l15 <= lrow);
                float pv = ok ? fexp2(v - mr) * il : 0.0f;
                sap[16 * jj] = pv;
                Ps[swz(16 * wg + quad * 4 + r, gc + 16 * jj + l15)] = f2bf(pv);
            }
        }
        // PV over this group's 32 s-cols: rows/cols of Ps are wave/group-private;
        // compiler's in-order lgkmcnt covers the RAW.
        short8 aP = *(const short8*)&Ps[swz(16 * wg + l15, gc + quad * 8)];
        const unsigned short* Vc = Vt + (cur << 12);
#pragma unroll
        for (int j = 0; j < 4; ++j) {
            short8 bv = *(const short8*)&Vc[swz(16 * j + l15, gc + quad * 8)];
            oacc[j] = __builtin_amdgcn_mfma_f32_16x16x32_bf16(aP, bv, oacc[j], 0, 0, 0);
        }
        if (st + 1 < ntiles) {   // write prefetched K and V^T to other buffer
            const int nb = (cur ^ 1) << 12;
            *(short8*)&Ks[nb + kswz] = pack8(kf0, kf1);
            unsigned short* Vn = Vt + nb;
            Vn[swz(sc + 0, sr)] = f2bf(vf0.x); Vn[swz(sc + 1, sr)] = f2bf(vf0.y);
            Vn[swz(sc + 2, sr)] = f2bf(vf0.z); Vn[swz(sc + 3, sr)] = f2bf(vf0.w);
            Vn[swz(sc + 4, sr)] = f2bf(vf1.x); Vn[swz(sc + 5, sr)] = f2bf(vf1.y);
            Vn[swz(sc + 6, sr)] = f2bf(vf1.z); Vn[swz(sc + 7, sr)] = f2bf(vf1.w);
        }
        __syncthreads();
    }

    // ---- combine partial O across groups (Ob overlays Ks/Vt; safe after barrier) ----
    if (g == 1) {
#pragma unroll
        for (int r = 0; r < 4; ++r) {
            const int row = 16 * wg + quad * 4 + r;
#pragma unroll
            for (int j = 0; j < 4; ++j)
                Ob[row * 65 + 16 * j + l15] = oacc[j][r];
        }
    }
    __syncthreads();
    if (g == 0) {
#pragma unroll
        for (int r = 0; r < 4; ++r) {
            const int row = 16 * wg + quad * 4 + r;
            float* op = outV + ((size_t)b * L_DIM + q0 + row) * ROWSTRIDE + h * 64 + l15;
#pragma unroll
            for (int j = 0; j < 4; ++j)
                op[16 * j] = oacc[j][r] + Ob[row * 65 + 16 * j + l15];
        }
    }

    // ---- zero-fill SA above the diagonal tile (d_out is poisoned) ----
    {
        const int z0 = ntiles << 6;
        const int zr = t >> 3;               // 64 rows, 8 threads/row
        float* rowp = saBase + (size_t)(q0 + zr) * L_DIM;
        const float4 zf = {0.f, 0.f, 0.f, 0.f};
        for (int s = z0 + (t & 7) * 4; s < L_DIM; s += 32)
            *(float4*)(rowp + s) = zf;
    }
}

extern "C" void kernel_launch(void* const* d_in, const int* in_sizes, int n_in,
                              void* d_out, int out_size, void* d_ws, size_t ws_size,
                              hipStream_t stream) {
    const float* Q  = (const float*)d_in[0];
    const float* K  = (const float*)d_in[1];
    const float* Vv = (const float*)d_in[2];
    float* out   = (float*)d_out;
    float* outV  = out;                                       // [B,L,H,E]
    float* outSA = out + (size_t)2 * L_DIM * H_DIM * 64;      // [B,H,L,S]

    dim3 grid(512);   // (c, c+256) co-resident pairs get complementary q-tiles
    dim3 block(NT);
    attn_mfma4<<<grid, block, 0, stream>>>(Q, K, Vv, outV, outSA);
}

// Round 3
// 330.500 us; speedup vs baseline: 1.2915x; 1.0547x over previous
//
#include <hip/hip_runtime.h>
#include <math.h>

// B=2, L=2048, H=8, E=64. Outputs: V [B,L,H,E] then SA [B,H,L,S], fp32.
#define L_DIM 2048
#define H_DIM 8
#define ROWSTRIDE 512                 // H*E floats between consecutive l
#define NT 512
// 0.125 * log2(e): scores computed in log2 domain -> raw v_exp_f32 for softmax
#define QSCALE 0.18033688011112042f
#define FLT_BIG 3.402823466e+38f

typedef __attribute__((ext_vector_type(8))) short short8;
typedef __attribute__((ext_vector_type(4))) float floatx4;

__device__ __forceinline__ float fexp2(float x) {
#if __has_builtin(__builtin_amdgcn_exp2f)
    return __builtin_amdgcn_exp2f(x);   // raw v_exp_f32
#else
    return exp2f(x);
#endif
}

__device__ __forceinline__ float flog2(float x) {
#if __has_builtin(__builtin_amdgcn_logf)
    return __builtin_amdgcn_logf(x);    // raw v_log_f32 (base-2)
#else
    return log2f(x);
#endif
}

// packed fp32x2 -> bf16x2 (RNE), one VALU op for two elements
__device__ __forceinline__ unsigned int cvtpk(float lo, float hi) {
    unsigned int r;
    asm("v_cvt_pk_bf16_f32 %0, %1, %2" : "=v"(r) : "v"(lo), "v"(hi));
    return r;
}

__device__ __forceinline__ short8 pack8(float4 a, float4 b) {
    union { unsigned int u[4]; short8 v; } pk;
    pk.u[0] = cvtpk(a.x, a.y); pk.u[1] = cvtpk(a.z, a.w);
    pk.u[2] = cvtpk(b.x, b.y); pk.u[3] = cvtpk(b.z, b.w);
    return pk.v;
}

__device__ __forceinline__ short8 pack8q(float4 a, float4 b) {
    union { unsigned int u[4]; short8 v; } pk;
    pk.u[0] = cvtpk(a.x * QSCALE, a.y * QSCALE);
    pk.u[1] = cvtpk(a.z * QSCALE, a.w * QSCALE);
    pk.u[2] = cvtpk(b.x * QSCALE, b.y * QSCALE);
    pk.u[3] = cvtpk(b.z * QSCALE, b.w * QSCALE);
    return pk.v;
}

// Swizzled short-index within a [64][64] bf16 tile. Rows are 128B = 8 x 16B
// blocks; phys block = logical block ^ (row&7). All ds_read_b128 fragment
// reads then hit the 8-access/bank floor. Bijective per row.
__device__ __forceinline__ int swz(int row, int col) {
    return (row << 6) + ((((col >> 3) ^ (row & 7)) << 3) | (col & 7));
}

// 512 blocks x 512 threads (8 waves). c=bid&255, hf=bid>>8, bh=c&15 (head
// pinned to one XCD; K+V of 2 (b,h) = 2MB L2-resident), qt = hf ? p : 31-p
// so natural (c, c+256) co-residency pairs complementary q-tiles (uniform 33
// tiles/pass per CU).
// All 8 waves share ONE staged 64x64 K (and V^T) tile; the two 4-wave
// s-groups split s-columns 32/32. Single barrier per iteration with
// register-held prefetch (T14).
// Pass 1 uses PER-LANE online (m,l): each lane tracks only the s-columns it
// owns -> zero cross-lane ops in the loop; one 4-round LSE merge at pass end
// (replaces 32 ds_bpermute per wave-iter). m init = -FLT_BIG keeps all
// exponents finite (no NaN guards needed).
__global__ __launch_bounds__(NT, 4)
void attn_mfma5(const float* __restrict__ Q, const float* __restrict__ K,
                const float* __restrict__ Vv, float* __restrict__ outV,
                float* __restrict__ outSA)
{
    __shared__ __align__(16) unsigned char smem[41984];
    unsigned short* Ks = (unsigned short*)(smem);           // [2 buf][64][64] swz, row=s col=e
    unsigned short* Vt = (unsigned short*)(smem + 16384);   // [2 buf][64][64] swz, row=e col=s
    unsigned short* Ps = (unsigned short*)(smem + 32768);   // [64][64] swz (wave/group-private slices)
    float* Ml = (float*)(smem + 40960);                     // [2][64]
    float* Ll = (float*)(smem + 41472);                     // [2][64]
    float* Ob = (float*)(smem);                             // [64][65] fp32, overlays Ks/Vt head

    const int t    = threadIdx.x;
    const int lane = t & 63;
    const int w    = t >> 6;           // wave 0..7
    const int g    = w >> 2;           // s-column group: cols [32g, 32g+32)
    const int wg   = w & 3;            // wave-in-group: rows 16wg..16wg+15
    const int l15  = lane & 15;
    const int quad = lane >> 4;
    const int gc   = g << 5;           // group column base within tile

    const int bid = blockIdx.x;
    const int c   = bid & 255;
    const int hf  = bid >> 8;
    const int bh  = c & 15;
    const int p   = c >> 4;
    const int qt  = hf ? p : (31 - p);
    const int h   = bh & 7;
    const int b   = bh >> 3;
    const int q0  = qt << 6;
    const int ntiles = qt + 1;

    const float* Qb = Q  + (size_t)b * L_DIM * ROWSTRIDE + h * 64;
    const float* Kb = K  + (size_t)b * L_DIM * ROWSTRIDE + h * 64;
    const float* Vb = Vv + (size_t)b * L_DIM * ROWSTRIDE + h * 64;
    float* saBase = outSA + (size_t)(b * H_DIM + h) * L_DIM * L_DIM;

    // staging mapping: thread t handles tile row sr, 8 elems at col sc
    const int sr = t >> 3, sc = (t & 7) << 3;
    const int kswz = swz(sr, sc);      // 16B-aligned short8 dest for K staging

    // ---- Q fragments straight from global (scale folded), once per block ----
    short8 aQ0, aQ1;
    {
        const float* qsrc = Qb + (size_t)(q0 + 16 * wg + l15) * ROWSTRIDE + quad * 8;
        aQ0 = pack8q(*(const float4*)(qsrc),      *(const float4*)(qsrc + 4));
        aQ1 = pack8q(*(const float4*)(qsrc + 32), *(const float4*)(qsrc + 36));
    }

    // =================== PASS 1: row max & denom (per-lane online) ===================
    float m_r[4], l_r[4];
#pragma unroll
    for (int r = 0; r < 4; ++r) { m_r[r] = -FLT_BIG; l_r[r] = 0.f; }

    {   // prologue: stage K tile 0 into buf 0
        const float* src = Kb + (size_t)sr * ROWSTRIDE + sc;
        *(short8*)&Ks[kswz] = pack8(*(const float4*)src, *(const float4*)(src + 4));
    }
    __syncthreads();

    for (int st = 0; st < ntiles; ++st) {
        const int cur = st & 1;
        // prefetch next K tile into regs (clamped addr on last iter)
        const int stp = (st + 1 < ntiles) ? (st + 1) : st;
        const float* ksrc = Kb + (size_t)((stp << 6) + sr) * ROWSTRIDE + sc;
        float4 kf0 = *(const float4*)(ksrc);
        float4 kf1 = *(const float4*)(ksrc + 4);

        const unsigned short* Kc = Ks + (cur << 12);
        floatx4 d[2];
#pragma unroll
        for (int jj = 0; jj < 2; ++jj) {
            const int sb = gc + (jj << 4) + l15;
            short8 b0 = *(const short8*)&Kc[swz(sb, quad * 8)];
            short8 b1 = *(const short8*)&Kc[swz(sb, 32 + quad * 8)];
            floatx4 acc = {0.f, 0.f, 0.f, 0.f};
            acc = __builtin_amdgcn_mfma_f32_16x16x32_bf16(aQ0, b0, acc, 0, 0, 0);
            acc = __builtin_amdgcn_mfma_f32_16x16x32_bf16(aQ1, b1, acc, 0, 0, 0);
            d[jj] = acc;
        }
        if (st == qt) {           // diagonal tile: mask, then per-lane update
            const int s0 = st << 6;
#pragma unroll
            for (int r = 0; r < 4; ++r) {
                const int lrow = q0 + 16 * wg + quad * 4 + r;
                float v0 = (s0 + gc +  0 + l15 <= lrow) ? d[0][r] : -INFINITY;
                float v1 = (s0 + gc + 16 + l15 <= lrow) ? d[1][r] : -INFINITY;
                const float mnew = fmaxf(m_r[r], fmaxf(v0, v1));  // >= -FLT_BIG, finite
                float es = fexp2(v0 - mnew) + fexp2(v1 - mnew);   // exp2(-inf)=0
                l_r[r] = l_r[r] * fexp2(m_r[r] - mnew) + es;
                m_r[r] = mnew;
            }
        } else {
#pragma unroll
            for (int r = 0; r < 4; ++r) {
                float v0 = d[0][r], v1 = d[1][r];
                const float mnew = fmaxf(m_r[r], fmaxf(v0, v1));
                float es = fexp2(v0 - mnew) + fexp2(v1 - mnew);
                l_r[r] = l_r[r] * fexp2(m_r[r] - mnew) + es;
                m_r[r] = mnew;
            }
        }
        if (st + 1 < ntiles)
            *(short8*)&Ks[((cur ^ 1) << 12) + kswz] = pack8(kf0, kf1);
        __syncthreads();
    }

    // ---- merge (m,l) across the 16 lanes owning this row's s-columns ----
#pragma unroll
    for (int r = 0; r < 4; ++r) {
#pragma unroll
        for (int mk = 1; mk < 16; mk <<= 1) {
            float mo = __shfl_xor(m_r[r], mk);
            float lo = __shfl_xor(l_r[r], mk);
            float mn = fmaxf(m_r[r], mo);      // finite always
            l_r[r] = l_r[r] * fexp2(m_r[r] - mn) + lo * fexp2(mo - mn);
            m_r[r] = mn;
        }
    }

    // ---- combine across the two s-column groups via LDS ----
    if (l15 == 0) {
#pragma unroll
        for (int r = 0; r < 4; ++r) {
            const int row = 16 * wg + quad * 4 + r;
            Ml[g * 64 + row] = m_r[r];
            Ll[g * 64 + row] = l_r[r];
        }
    }
    {   // pass-2 prologue: stage K and V^T tile 0 into buf 0 (overlaps combine)
        const float* src = Kb + (size_t)sr * ROWSTRIDE + sc;
        *(short8*)&Ks[kswz] = pack8(*(const float4*)src, *(const float4*)(src + 4));
        const float* vsrc = Vb + (size_t)sr * ROWSTRIDE + sc;
        float4 f0 = *(const float4*)(vsrc);
        float4 f1 = *(const float4*)(vsrc + 4);
        unsigned int w01 = cvtpk(f0.x, f0.y), w23 = cvtpk(f0.z, f0.w);
        unsigned int w45 = cvtpk(f1.x, f1.y), w67 = cvtpk(f1.z, f1.w);
        Vt[swz(sc + 0, sr)] = (unsigned short)w01;
        Vt[swz(sc + 1, sr)] = (unsigned short)(w01 >> 16);
        Vt[swz(sc + 2, sr)] = (unsigned short)w23;
        Vt[swz(sc + 3, sr)] = (unsigned short)(w23 >> 16);
        Vt[swz(sc + 4, sr)] = (unsigned short)w45;
        Vt[swz(sc + 5, sr)] = (unsigned short)(w45 >> 16);
        Vt[swz(sc + 6, sr)] = (unsigned short)w67;
        Vt[swz(sc + 7, sr)] = (unsigned short)(w67 >> 16);
    }
    __syncthreads();

    // c_r = m_final + log2(l_final): p = exp2(v - c_r), normalization folded
    float c_r[4];
#pragma unroll
    for (int r = 0; r < 4; ++r) {
        const int row = 16 * wg + quad * 4 + r;
        float m0 = Ml[row], m1 = Ml[64 + row];
        float l0 = Ll[row], l1 = Ll[64 + row];
        float mf = fmaxf(m0, m1);              // finite (never -inf)
        float lf = l0 * fexp2(m0 - mf) + l1 * fexp2(m1 - mf);  // >= 1 for real rows
        c_r[r] = mf + flog2(lf);
    }

    // =================== PASS 2: SA write + PV ===================
    floatx4 oacc[4];
#pragma unroll
    for (int j = 0; j < 4; ++j) oacc[j] = (floatx4){0.f, 0.f, 0.f, 0.f};

    for (int st = 0; st < ntiles; ++st) {
        const int cur = st & 1;
        const int stp = (st + 1 < ntiles) ? (st + 1) : st;
        const float* ksrc = Kb + (size_t)((stp << 6) + sr) * ROWSTRIDE + sc;
        const float* vsrc = Vb + (size_t)((stp << 6) + sr) * ROWSTRIDE + sc;
        float4 kf0 = *(const float4*)(ksrc);
        float4 kf1 = *(const float4*)(ksrc + 4);
        float4 vf0 = *(const float4*)(vsrc);
        float4 vf1 = *(const float4*)(vsrc + 4);

        const unsigned short* Kc = Ks + (cur << 12);
        floatx4 d[2];
#pragma unroll
        for (int jj = 0; jj < 2; ++jj) {
            const int sb = gc + (jj << 4) + l15;
            short8 b0 = *(const short8*)&Kc[swz(sb, quad * 8)];
            short8 b1 = *(const short8*)&Kc[swz(sb, 32 + quad * 8)];
            floatx4 acc = {0.f, 0.f, 0.f, 0.f};
            acc = __builtin_amdgcn_mfma_f32_16x16x32_bf16(aQ0, b0, acc, 0, 0, 0);
            acc = __builtin_amdgcn_mfma_f32_16x16x32_bf16(aQ1, b1, acc, 0, 0, 0);
            d[jj] = acc;
        }
        const int s0 = st << 6;
        if (st == qt) {           // diagonal tile: masked path
#pragma unroll
            for (int r = 0; r < 4; ++r) {
                const int lrow = q0 + 16 * wg + quad * 4 + r;
                float* sap = saBase + (size_t)lrow * L_DIM + s0 + gc + l15;
                const float cr = c_r[r];
                float p0 = (s0 + gc +      l15 <= lrow) ? fexp2(d[0][r] - cr) : 0.0f;
                float p1 = (s0 + gc + 16 + l15 <= lrow) ? fexp2(d[1][r] - cr) : 0.0f;
                sap[0] = p0; sap[16] = p1;
                unsigned int pw = cvtpk(p0, p1);
                const int prow = 16 * wg + quad * 4 + r;
                Ps[swz(prow, gc + l15)]      = (unsigned short)pw;
                Ps[swz(prow, gc + 16 + l15)] = (unsigned short)(pw >> 16);
            }
        } else {                  // interior tile: no masking
#pragma unroll
            for (int r = 0; r < 4; ++r) {
                const int lrow = q0 + 16 * wg + quad * 4 + r;
                float* sap = saBase + (size_t)lrow * L_DIM + s0 + gc + l15;
                const float cr = c_r[r];
                float p0 = fexp2(d[0][r] - cr);
                float p1 = fexp2(d[1][r] - cr);
                sap[0] = p0; sap[16] = p1;
                unsigned int pw = cvtpk(p0, p1);
                const int prow = 16 * wg + quad * 4 + r;
                Ps[swz(prow, gc + l15)]      = (unsigned short)pw;
                Ps[swz(prow, gc + 16 + l15)] = (unsigned short)(pw >> 16);
            }
        }
        // PV over this group's 32 s-cols: rows of Ps are wave-private;
        // compiler's in-order lgkmcnt covers the RAW.
        short8 aP = *(const short8*)&Ps[swz(16 * wg + l15, gc + quad * 8)];
        const unsigned short* Vc = Vt + (cur << 12);
#pragma unroll
        for (int j = 0; j < 4; ++j) {
            short8 bv = *(const short8*)&Vc[swz(16 * j + l15, gc + quad * 8)];
            oacc[j] = __builtin_amdgcn_mfma_f32_16x16x32_bf16(aP, bv, oacc[j], 0, 0, 0);
        }
        if (st + 1 < ntiles) {   // write prefetched K and V^T to other buffer
            const int nb = (cur ^ 1) << 12;
            *(short8*)&Ks[nb + kswz] = pack8(kf0, kf1);
            unsigned short* Vn = Vt + nb;
            unsigned int w01 = cvtpk(vf0.x, vf0.y), w23 = cvtpk(vf0.z, vf0.w);
            unsigned int w45 = cvtpk(vf1.x, vf1.y), w67 = cvtpk(vf1.z, vf1.w);
            Vn[swz(sc + 0, sr)] = (unsigned short)w01;
            Vn[swz(sc + 1, sr)] = (unsigned short)(w01 >> 16);
            Vn[swz(sc + 2, sr)] = (unsigned short)w23;
            Vn[swz(sc + 3, sr)] = (unsigned short)(w23 >> 16);
            Vn[swz(sc + 4, sr)] = (unsigned short)w45;
            Vn[swz(sc + 5, sr)] = (unsigned short)(w45 >> 16);
            Vn[swz(sc + 6, sr)] = (unsigned short)w67;
            Vn[swz(sc + 7, sr)] = (unsigned short)(w67 >> 16);
        }
        __syncthreads();
    }

    // ---- combine partial O across groups (Ob overlays Ks/Vt; safe after barrier) ----
    if (g == 1) {
#pragma unroll
        for (int r = 0; r < 4; ++r) {
            const int row = 16 * wg + quad * 4 + r;
#pragma unroll
            for (int j = 0; j < 4; ++j)
                Ob[row * 65 + 16 * j + l15] = oacc[j][r];
        }
    }
    __syncthreads();
    if (g == 0) {
#pragma unroll
        for (int r = 0; r < 4; ++r) {
            const int row = 16 * wg + quad * 4 + r;
            float* op = outV + ((size_t)b * L_DIM + q0 + row) * ROWSTRIDE + h * 64 + l15;
#pragma unroll
            for (int j = 0; j < 4; ++j)
                op[16 * j] = oacc[j][r] + Ob[row * 65 + 16 * j + l15];
        }
    }

    // ---- zero-fill SA above the diagonal tile (d_out is poisoned) ----
    {
        const int z0 = ntiles << 6;
        const int zr = t >> 3;               // 64 rows, 8 threads/row
        float* rowp = saBase + (size_t)(q0 + zr) * L_DIM;
        const float4 zf = {0.f, 0.f, 0.f, 0.f};
        for (int s = z0 + (t & 7) * 4; s < L_DIM; s += 32)
            *(float4*)(rowp + s) = zf;
    }
}

extern "C" void kernel_launch(void* const* d_in, const int* in_sizes, int n_in,
                              void* d_out, int out_size, void* d_ws, size_t ws_size,
                              hipStream_t stream) {
    const float* Q  = (const float*)d_in[0];
    const float* K  = (const float*)d_in[1];
    const float* Vv = (const float*)d_in[2];
    float* out   = (float*)d_out;
    float* outV  = out;                                       // [B,L,H,E]
    float* outSA = out + (size_t)2 * L_DIM * H_DIM * 64;      // [B,H,L,S]

    dim3 grid(512);   // (c, c+256) co-resident pairs get complementary q-tiles
    dim3 block(NT);
    attn_mfma5<<<grid, block, 0, stream>>>(Q, K, Vv, outV, outSA);
}

// Round 4
// 328.793 us; speedup vs baseline: 1.2982x; 1.0052x over previous
//
#include <hip/hip_runtime.h>
#include <math.h>

// B=2, L=2048, H=8, E=64. Outputs: V [B,L,H,E] then SA [B,H,L,S], fp32.
#define L_DIM 2048
#define H_DIM 8
#define ROWSTRIDE 512                 // H*E floats between consecutive l
#define NT 512
// 0.125 * log2(e): scores computed in log2 domain -> raw v_exp_f32 for softmax
#define QSCALE 0.18033688011112042f
#define FLT_BIG 3.402823466e+38f

typedef __attribute__((ext_vector_type(8))) short short8;
typedef __attribute__((ext_vector_type(4))) float floatx4;

__device__ __forceinline__ float fexp2(float x) {
#if __has_builtin(__builtin_amdgcn_exp2f)
    return __builtin_amdgcn_exp2f(x);   // raw v_exp_f32
#else
    return exp2f(x);
#endif
}

__device__ __forceinline__ float flog2(float x) {
#if __has_builtin(__builtin_amdgcn_logf)
    return __builtin_amdgcn_logf(x);    // raw v_log_f32 (base-2)
#else
    return log2f(x);
#endif
}

// packed fp32x2 -> bf16x2 (RNE), one VALU op for two elements
__device__ __forceinline__ unsigned int cvtpk(float lo, float hi) {
    unsigned int r;
    asm("v_cvt_pk_bf16_f32 %0, %1, %2" : "=v"(r) : "v"(lo), "v"(hi));
    return r;
}

__device__ __forceinline__ short8 pack8(float4 a, float4 b) {
    union { unsigned int u[4]; short8 v; } pk;
    pk.u[0] = cvtpk(a.x, a.y); pk.u[1] = cvtpk(a.z, a.w);
    pk.u[2] = cvtpk(b.x, b.y); pk.u[3] = cvtpk(b.z, b.w);
    return pk.v;
}

__device__ __forceinline__ short8 pack8q(float4 a, float4 b) {
    union { unsigned int u[4]; short8 v; } pk;
    pk.u[0] = cvtpk(a.x * QSCALE, a.y * QSCALE);
    pk.u[1] = cvtpk(a.z * QSCALE, a.w * QSCALE);
    pk.u[2] = cvtpk(b.x * QSCALE, b.y * QSCALE);
    pk.u[3] = cvtpk(b.z * QSCALE, b.w * QSCALE);
    return pk.v;
}

// Swizzled short-index within a [64][64] bf16 tile. Rows are 128B = 8 x 16B
// blocks; phys block = logical block ^ (row&7). Preserves col&7 (so b32/b128
// alignment holds). Bijective per row.
__device__ __forceinline__ int swz(int row, int col) {
    return (row << 6) + ((((col >> 3) ^ (row & 7)) << 3) | (col & 7));
}

// 512 blocks x 512 threads (8 waves). c=bid&255, hf=bid>>8, bh=c&15 (head
// pinned to one XCD; K+V of 2 (b,h) = 2MB L2-resident), qt = hf ? p : 31-p
// so natural (c, c+256) co-residency pairs complementary q-tiles (uniform 33
// tiles/pass per CU).
// 8 waves share ONE staged 64x64 K (and V^T) tile; two 4-wave s-groups split
// s-columns 32/32.
// Round-4 changes (LDS-pipe + phase-overhead bound per round-3 analysis):
//  * s-pairing: K staged row-permuted so QK frag jj, lane l15 <-> s-col
//    2*l15+jj. Lane's (p0,p1) adjacent -> Ps writes 4x b32 (was 8x b16),
//    SA stores 4x dwordx2 (was 8x dword, now 128B segments).
//  * paired V staging: thread loads 2 s-rows x 4 e, writes cvtpk pairs ->
//    4x b32 (was 8x b16 + 8 extracts).
//  * 2-tile phases in both passes (4-buffer pair double-buffer): barriers
//    halve, prefetch covered by two tile-computes.
__global__ __launch_bounds__(NT, 4)
void attn_mfma6(const float* __restrict__ Q, const float* __restrict__ K,
                const float* __restrict__ Vv, float* __restrict__ outV,
                float* __restrict__ outSA)
{
    __shared__ __align__(16) unsigned char smem[74752];
    unsigned short* Ks = (unsigned short*)(smem);           // [4 buf][64][64] swz, row-permuted s
    unsigned short* Vt = (unsigned short*)(smem + 32768);   // [4 buf][64][64] swz, row=e col=s
    unsigned short* Ps = (unsigned short*)(smem + 65536);   // [64][64] swz
    float* Ml = (float*)(smem + 73728);                     // [2][64]
    float* Ll = (float*)(smem + 74240);                     // [2][64]
    float* Ob = (float*)(smem);                             // [64][65] fp32, overlays Ks

    const int t    = threadIdx.x;
    const int lane = t & 63;
    const int w    = t >> 6;           // wave 0..7
    const int g    = w >> 2;           // s-column group: cols [32g, 32g+32)
    const int wg   = w & 3;            // wave-in-group: rows 16wg..16wg+15
    const int l15  = lane & 15;
    const int quad = lane >> 4;
    const int gc   = g << 5;           // group column base within tile

    const int bid = blockIdx.x;
    const int c   = bid & 255;
    const int hf  = bid >> 8;
    const int bh  = c & 15;
    const int p   = c >> 4;
    const int qt  = hf ? p : (31 - p);
    const int h   = bh & 7;
    const int b   = bh >> 3;
    const int q0  = qt << 6;
    const int ntiles = qt + 1;
    const int nphase = (ntiles + 1) >> 1;

    const float* Qb = Q  + (size_t)b * L_DIM * ROWSTRIDE + h * 64;
    const float* Kb = K  + (size_t)b * L_DIM * ROWSTRIDE + h * 64;
    const float* Vb = Vv + (size_t)b * L_DIM * ROWSTRIDE + h * 64;
    float* saBase = outSA + (size_t)(b * H_DIM + h) * L_DIM * L_DIM;

    // ---- K staging map: thread handles logical s-row sr, 8 e at col sc.
    // Row-permute within each 32-row group: k=sr&31 -> phys (k&1)*16+(k>>1),
    // so frag jj, lane l15 reads s = gc + 2*l15 + jj.
    const int sr = t >> 3, sc = (t & 7) << 3;
    const int kq = sr & 31;
    const int kpr = (sr & 32) | ((kq & 1) << 4) | (kq >> 1);
    const int kswz = swz(kpr, sc);     // 16B-aligned short8 dest

    // ---- V staging map: thread handles s-rows {2rp, 2rp+1}, 4 e at ec.
    const int rp = t >> 4, ec = (t & 15) << 2;
    const int vswz0 = swz(ec + 0, 2 * rp);   // b32-aligned (col even)
    const int vswz1 = swz(ec + 1, 2 * rp);
    const int vswz2 = swz(ec + 2, 2 * rp);
    const int vswz3 = swz(ec + 3, 2 * rp);

    auto stageK = [&](int bufi, float4 f0, float4 f1) {
        *(short8*)&Ks[(bufi << 12) + kswz] = pack8(f0, f1);
    };
    auto stageV = [&](int bufi, float4 a, float4 bb) {
        unsigned short* Vn = Vt + (bufi << 12);
        *(unsigned int*)&Vn[vswz0] = cvtpk(a.x, bb.x);
        *(unsigned int*)&Vn[vswz1] = cvtpk(a.y, bb.y);
        *(unsigned int*)&Vn[vswz2] = cvtpk(a.z, bb.z);
        *(unsigned int*)&Vn[vswz3] = cvtpk(a.w, bb.w);
    };

    // ---- Q fragments straight from global (scale folded), once per block ----
    short8 aQ0, aQ1;
    {
        const float* qsrc = Qb + (size_t)(q0 + 16 * wg + l15) * ROWSTRIDE + quad * 8;
        aQ0 = pack8q(*(const float4*)(qsrc),      *(const float4*)(qsrc + 4));
        aQ1 = pack8q(*(const float4*)(qsrc + 32), *(const float4*)(qsrc + 36));
    }

    // =================== PASS 1: row max & denom (per-lane online) ===================
    float m_r[4], l_r[4];
#pragma unroll
    for (int r = 0; r < 4; ++r) { m_r[r] = -FLT_BIG; l_r[r] = 0.f; }

    auto compute1 = [&](int bufi, int st) {
        const unsigned short* Kc = Ks + (bufi << 12);
        floatx4 d0, d1;
        {
            short8 b0 = *(const short8*)&Kc[swz(gc + l15, quad * 8)];
            short8 b1 = *(const short8*)&Kc[swz(gc + l15, 32 + quad * 8)];
            floatx4 acc = {0.f, 0.f, 0.f, 0.f};
            acc = __builtin_amdgcn_mfma_f32_16x16x32_bf16(aQ0, b0, acc, 0, 0, 0);
            acc = __builtin_amdgcn_mfma_f32_16x16x32_bf16(aQ1, b1, acc, 0, 0, 0);
            d0 = acc;
        }
        {
            short8 b0 = *(const short8*)&Kc[swz(gc + 16 + l15, quad * 8)];
            short8 b1 = *(const short8*)&Kc[swz(gc + 16 + l15, 32 + quad * 8)];
            floatx4 acc = {0.f, 0.f, 0.f, 0.f};
            acc = __builtin_amdgcn_mfma_f32_16x16x32_bf16(aQ0, b0, acc, 0, 0, 0);
            acc = __builtin_amdgcn_mfma_f32_16x16x32_bf16(aQ1, b1, acc, 0, 0, 0);
            d1 = acc;
        }
        if (st == qt) {          // diagonal tile: mask (s = s0+gc+2*l15 {+1})
            const int scol = (st << 6) + gc + 2 * l15;
#pragma unroll
            for (int r = 0; r < 4; ++r) {
                const int lrow = q0 + 16 * wg + quad * 4 + r;
                float v0 = (scol     <= lrow) ? d0[r] : -INFINITY;
                float v1 = (scol + 1 <= lrow) ? d1[r] : -INFINITY;
                const float mnew = fmaxf(m_r[r], fmaxf(v0, v1));  // finite
                float es = fexp2(v0 - mnew) + fexp2(v1 - mnew);   // exp2(-inf)=0
                l_r[r] = l_r[r] * fexp2(m_r[r] - mnew) + es;
                m_r[r] = mnew;
            }
        } else {
#pragma unroll
            for (int r = 0; r < 4; ++r) {
                float v0 = d0[r], v1 = d1[r];
                const float mnew = fmaxf(m_r[r], fmaxf(v0, v1));
                float es = fexp2(v0 - mnew) + fexp2(v1 - mnew);
                l_r[r] = l_r[r] * fexp2(m_r[r] - mnew) + es;
                m_r[r] = mnew;
            }
        }
    };

    {   // prologue: stage tiles 0 and 1 (dup tile 0 if ntiles==1)
        const int t1 = (ntiles > 1) ? 1 : 0;
        const float* k0 = Kb + (size_t)sr * ROWSTRIDE + sc;
        const float* k1 = Kb + (size_t)((t1 << 6) + sr) * ROWSTRIDE + sc;
        stageK(0, *(const float4*)k0, *(const float4*)(k0 + 4));
        stageK(1, *(const float4*)k1, *(const float4*)(k1 + 4));
    }
    __syncthreads();

    for (int ph = 0; ph < nphase; ++ph) {
        const int base = ph << 1;
        const int pb   = (ph & 1) << 1;
        // prefetch next pair into regs (clamped addresses on the tail)
        const int t2 = (base + 2 < ntiles) ? base + 2 : ntiles - 1;
        const int t3 = (base + 3 < ntiles) ? base + 3 : ntiles - 1;
        const float* k2 = Kb + (size_t)((t2 << 6) + sr) * ROWSTRIDE + sc;
        const float* k3 = Kb + (size_t)((t3 << 6) + sr) * ROWSTRIDE + sc;
        float4 a2 = *(const float4*)k2, b2 = *(const float4*)(k2 + 4);
        float4 a3 = *(const float4*)k3, b3 = *(const float4*)(k3 + 4);

        compute1(pb, base);
        if (base + 1 < ntiles) compute1(pb + 1, base + 1);

        if (base + 2 < ntiles) stageK(pb ^ 2, a2, b2);
        if (base + 3 < ntiles) stageK((pb ^ 2) + 1, a3, b3);
        __syncthreads();
    }

    // ---- merge (m,l) across the 16 lanes owning this row's s-columns ----
#pragma unroll
    for (int r = 0; r < 4; ++r) {
#pragma unroll
        for (int mk = 1; mk < 16; mk <<= 1) {
            float mo = __shfl_xor(m_r[r], mk);
            float lo = __shfl_xor(l_r[r], mk);
            float mn = fmaxf(m_r[r], mo);      // finite always
            l_r[r] = l_r[r] * fexp2(m_r[r] - mn) + lo * fexp2(mo - mn);
            m_r[r] = mn;
        }
    }

    // ---- combine across the two s-column groups via LDS ----
    if (l15 == 0) {
#pragma unroll
        for (int r = 0; r < 4; ++r) {
            const int row = 16 * wg + quad * 4 + r;
            Ml[g * 64 + row] = m_r[r];
            Ll[g * 64 + row] = l_r[r];
        }
    }
    {   // pass-2 prologue: stage K and V^T tiles 0,1 (overlaps m/l combine)
        const int t1 = (ntiles > 1) ? 1 : 0;
        const float* k0 = Kb + (size_t)sr * ROWSTRIDE + sc;
        const float* k1 = Kb + (size_t)((t1 << 6) + sr) * ROWSTRIDE + sc;
        stageK(0, *(const float4*)k0, *(const float4*)(k0 + 4));
        stageK(1, *(const float4*)k1, *(const float4*)(k1 + 4));
        const float* v0p = Vb + (size_t)(2 * rp) * ROWSTRIDE + ec;
        const float* v1p = Vb + (size_t)((t1 << 6) + 2 * rp) * ROWSTRIDE + ec;
        stageV(0, *(const float4*)v0p, *(const float4*)(v0p + ROWSTRIDE));
        stageV(1, *(const float4*)v1p, *(const float4*)(v1p + ROWSTRIDE));
    }
    __syncthreads();

    // c_r = m_final + log2(l_final): p = exp2(v - c_r), normalization folded
    float c_r[4];
#pragma unroll
    for (int r = 0; r < 4; ++r) {
        const int row = 16 * wg + quad * 4 + r;
        float m0 = Ml[row], m1 = Ml[64 + row];
        float l0 = Ll[row], l1 = Ll[64 + row];
        float mf = fmaxf(m0, m1);              // finite (never -inf)
        float lf = l0 * fexp2(m0 - mf) + l1 * fexp2(m1 - mf);  // 0 contrib for all-masked group
        c_r[r] = mf + flog2(lf);
    }

    // =================== PASS 2: SA write + PV ===================
    floatx4 oacc[4];
#pragma unroll
    for (int j = 0; j < 4; ++j) oacc[j] = (floatx4){0.f, 0.f, 0.f, 0.f};

    auto compute2 = [&](int bufi, int st) {
        const unsigned short* Kc = Ks + (bufi << 12);
        const unsigned short* Vc = Vt + (bufi << 12);
        floatx4 d0, d1;
        {
            short8 b0 = *(const short8*)&Kc[swz(gc + l15, quad * 8)];
            short8 b1 = *(const short8*)&Kc[swz(gc + l15, 32 + quad * 8)];
            floatx4 acc = {0.f, 0.f, 0.f, 0.f};
            acc = __builtin_amdgcn_mfma_f32_16x16x32_bf16(aQ0, b0, acc, 0, 0, 0);
            acc = __builtin_amdgcn_mfma_f32_16x16x32_bf16(aQ1, b1, acc, 0, 0, 0);
            d0 = acc;
        }
        {
            short8 b0 = *(const short8*)&Kc[swz(gc + 16 + l15, quad * 8)];
            short8 b1 = *(const short8*)&Kc[swz(gc + 16 + l15, 32 + quad * 8)];
            floatx4 acc = {0.f, 0.f, 0.f, 0.f};
            acc = __builtin_amdgcn_mfma_f32_16x16x32_bf16(aQ0, b0, acc, 0, 0, 0);
            acc = __builtin_amdgcn_mfma_f32_16x16x32_bf16(aQ1, b1, acc, 0, 0, 0);
            d1 = acc;
        }
        const int s0 = st << 6;
        const int scol = s0 + gc + 2 * l15;
        if (st == qt) {          // diagonal tile: masked path
#pragma unroll
            for (int r = 0; r < 4; ++r) {
                const int lrow = q0 + 16 * wg + quad * 4 + r;
                const float cr = c_r[r];
                float p0 = (scol     <= lrow) ? fexp2(d0[r] - cr) : 0.0f;
                float p1 = (scol + 1 <= lrow) ? fexp2(d1[r] - cr) : 0.0f;
                float2 pr; pr.x = p0; pr.y = p1;
                *(float2*)(saBase + (size_t)lrow * L_DIM + scol) = pr;
                *(unsigned int*)&Ps[swz(16 * wg + quad * 4 + r, gc + 2 * l15)] = cvtpk(p0, p1);
            }
        } else {                 // interior tile: no masking
#pragma unroll
            for (int r = 0; r < 4; ++r) {
                const int lrow = q0 + 16 * wg + quad * 4 + r;
                const float cr = c_r[r];
                float p0 = fexp2(d0[r] - cr);
                float p1 = fexp2(d1[r] - cr);
                float2 pr; pr.x = p0; pr.y = p1;
                *(float2*)(saBase + (size_t)lrow * L_DIM + scol) = pr;
                *(unsigned int*)&Ps[swz(16 * wg + quad * 4 + r, gc + 2 * l15)] = cvtpk(p0, p1);
            }
        }
        // PV over this group's 32 s-cols: Ps rows/col-halves are wave-private;
        // compiler's in-order lgkmcnt covers the RAW.
        short8 aP = *(const short8*)&Ps[swz(16 * wg + l15, gc + quad * 8)];
#pragma unroll
        for (int j = 0; j < 4; ++j) {
            short8 bv = *(const short8*)&Vc[swz(16 * j + l15, gc + quad * 8)];
            oacc[j] = __builtin_amdgcn_mfma_f32_16x16x32_bf16(aP, bv, oacc[j], 0, 0, 0);
        }
    };

    for (int ph = 0; ph < nphase; ++ph) {
        const int base = ph << 1;
        const int pb   = (ph & 1) << 1;
        const int t2 = (base + 2 < ntiles) ? base + 2 : ntiles - 1;
        const int t3 = (base + 3 < ntiles) ? base + 3 : ntiles - 1;
        const float* k2 = Kb + (size_t)((t2 << 6) + sr) * ROWSTRIDE + sc;
        const float* k3 = Kb + (size_t)((t3 << 6) + sr) * ROWSTRIDE + sc;
        const float* v2 = Vb + (size_t)((t2 << 6) + 2 * rp) * ROWSTRIDE + ec;
        const float* v3 = Vb + (size_t)((t3 << 6) + 2 * rp) * ROWSTRIDE + ec;
        float4 ka2 = *(const float4*)k2, kb2 = *(const float4*)(k2 + 4);
        float4 ka3 = *(const float4*)k3, kb3 = *(const float4*)(k3 + 4);
        float4 va2 = *(const float4*)v2, vb2 = *(const float4*)(v2 + ROWSTRIDE);
        float4 va3 = *(const float4*)v3, vb3 = *(const float4*)(v3 + ROWSTRIDE);

        compute2(pb, base);
        if (base + 1 < ntiles) compute2(pb + 1, base + 1);

        if (base + 2 < ntiles) { stageK(pb ^ 2, ka2, kb2); stageV(pb ^ 2, va2, vb2); }
        if (base + 3 < ntiles) { stageK((pb ^ 2) + 1, ka3, kb3); stageV((pb ^ 2) + 1, va3, vb3); }
        __syncthreads();
    }

    // ---- combine partial O across groups (Ob overlays Ks; safe after barrier) ----
    if (g == 1) {
#pragma unroll
        for (int r = 0; r < 4; ++r) {
            const int row = 16 * wg + quad * 4 + r;
#pragma unroll
            for (int j = 0; j < 4; ++j)
                Ob[row * 65 + 16 * j + l15] = oacc[j][r];
        }
    }
    __syncthreads();
    if (g == 0) {
#pragma unroll
        for (int r = 0; r < 4; ++r) {
            const int row = 16 * wg + quad * 4 + r;
            float* op = outV + ((size_t)b * L_DIM + q0 + row) * ROWSTRIDE + h * 64 + l15;
#pragma unroll
            for (int j = 0; j < 4; ++j)
                op[16 * j] = oacc[j][r] + Ob[row * 65 + 16 * j + l15];
        }
    }

    // ---- zero-fill SA above the diagonal tile (d_out is poisoned) ----
    {
        const int z0 = ntiles << 6;
        const int zr = t >> 3;               // 64 rows, 8 threads/row
        float* rowp = saBase + (size_t)(q0 + zr) * L_DIM;
        const float4 zf = {0.f, 0.f, 0.f, 0.f};
        for (int s = z0 + (t & 7) * 4; s < L_DIM; s += 32)
            *(float4*)(rowp + s) = zf;
    }
}

extern "C" void kernel_launch(void* const* d_in, const int* in_sizes, int n_in,
                              void* d_out, int out_size, void* d_ws, size_t ws_size,
                              hipStream_t stream) {
    const float* Q  = (const float*)d_in[0];
    const float* K  = (const float*)d_in[1];
    const float* Vv = (const float*)d_in[2];
    float* out   = (float*)d_out;
    float* outV  = out;                                       // [B,L,H,E]
    float* outSA = out + (size_t)2 * L_DIM * H_DIM * 64;      // [B,H,L,S]

    dim3 grid(512);   // (c, c+256) co-resident pairs get complementary q-tiles
    dim3 block(NT);
    attn_mfma6<<<grid, block, 0, stream>>>(Q, K, Vv, outV, outSA);
}